// Round 1
// baseline (245.716 us; speedup 1.0000x reference)
//
#include <hip/hip_runtime.h>
#include <hip/hip_bf16.h>

#define BB 4096
#define DD 512
#define NSLICE 8
#define JW (BB / NSLICE)  // 512

typedef unsigned short u16;
typedef unsigned int u32;

using f32x4 = __attribute__((ext_vector_type(4))) float;
using bf16x8 = __attribute__((ext_vector_type(8))) short;

// exp scaling: p = exp2((s-1)*100*log2e + 64)  -> all normal-range for s in [-0.44, 1]
// lse = 100 - 64*ln2 + ln(sum p)
constexpr float CEXP = 144.26950408889634f;          // 100 * log2(e)
constexpr float EOFF = 64.0f - 144.26950408889634f;  // bias - CEXP
constexpr float LN2 = 0.6931471805599453f;
constexpr float LSE_BASE = 100.0f - 64.0f * 0.6931471805599453f;  // 55.63858...

__device__ __forceinline__ float wave_sum(float v) {
#pragma unroll
  for (int m = 1; m < 64; m <<= 1) v += __shfl_xor(v, m);
  return v;
}

__device__ __forceinline__ float bfu(u16 u) {
  return __builtin_bit_cast(float, (u32)u << 16);
}

__device__ __forceinline__ u16 f2bf(float f) {
  __hip_bfloat16 h = __float2bfloat16(f);
  return __builtin_bit_cast(u16, h);
}

// ---------------- kernel 1: row L2-normalize (fp32) -> bf16, plus fp32 pos ----------------
__global__ __launch_bounds__(64) void k_norm(const float* __restrict__ feat,
                                             const float* __restrict__ feat_old,
                                             u16* __restrict__ fnb, u16* __restrict__ fob,
                                             float* __restrict__ pos) {
  const int i = blockIdx.x;
  const int t = threadIdx.x;
  const float4 x0 = *(const float4*)(feat + (size_t)i * DD + t * 4);
  const float4 x1 = *(const float4*)(feat + (size_t)i * DD + 256 + t * 4);
  const float4 y0 = *(const float4*)(feat_old + (size_t)i * DD + t * 4);
  const float4 y1 = *(const float4*)(feat_old + (size_t)i * DD + 256 + t * 4);
  float sx = x0.x * x0.x + x0.y * x0.y + x0.z * x0.z + x0.w * x0.w +
             x1.x * x1.x + x1.y * x1.y + x1.z * x1.z + x1.w * x1.w;
  float sy = y0.x * y0.x + y0.y * y0.y + y0.z * y0.z + y0.w * y0.w +
             y1.x * y1.x + y1.y * y1.y + y1.z * y1.z + y1.w * y1.w;
  float sxy = x0.x * y0.x + x0.y * y0.y + x0.z * y0.z + x0.w * y0.w +
              x1.x * y1.x + x1.y * y1.y + x1.z * y1.z + x1.w * y1.w;
  sx = wave_sum(sx);
  sy = wave_sum(sy);
  sxy = wave_sum(sxy);
  const float inx = 1.0f / fmaxf(sqrtf(sx), 1e-12f);
  const float iny = 1.0f / fmaxf(sqrtf(sy), 1e-12f);
  ushort4 ox0, ox1, oy0, oy1;
  ox0.x = f2bf(x0.x * inx); ox0.y = f2bf(x0.y * inx);
  ox0.z = f2bf(x0.z * inx); ox0.w = f2bf(x0.w * inx);
  ox1.x = f2bf(x1.x * inx); ox1.y = f2bf(x1.y * inx);
  ox1.z = f2bf(x1.z * inx); ox1.w = f2bf(x1.w * inx);
  oy0.x = f2bf(y0.x * iny); oy0.y = f2bf(y0.y * iny);
  oy0.z = f2bf(y0.z * iny); oy0.w = f2bf(y0.w * iny);
  oy1.x = f2bf(y1.x * iny); oy1.y = f2bf(y1.y * iny);
  oy1.z = f2bf(y1.z * iny); oy1.w = f2bf(y1.w * iny);
  *(ushort4*)(fnb + (size_t)i * DD + t * 4) = ox0;
  *(ushort4*)(fnb + (size_t)i * DD + 256 + t * 4) = ox1;
  *(ushort4*)(fob + (size_t)i * DD + t * 4) = oy0;
  *(ushort4*)(fob + (size_t)i * DD + 256 + t * 4) = oy1;
  if (t == 0) pos[i] = sxy * inx * iny;
}

// ---------------- kernel 2: fused dual-GEMM + exp2 partial sums ----------------
// grid (64 row-tiles, NSLICE j-slices), 256 threads (4 waves, 2x2 of 32x32 each)
__global__ __launch_bounds__(256) void k_fused(const u16* __restrict__ fnb,
                                               const u16* __restrict__ fob,
                                               float* __restrict__ partial) {
  __shared__ __align__(16) u16 lA[64 * 64];
  __shared__ __align__(16) u16 lB1[64 * 64];
  __shared__ __align__(16) u16 lB2[64 * 64];
  const int tid = threadIdx.x;
  const int lane = tid & 63;
  const int wid = tid >> 6;
  const int wr = wid >> 1, wc = wid & 1;
  const int row0 = blockIdx.x * 64;
  const int js = blockIdx.y;
  const int lrow = lane & 15;
  const int lkg = lane >> 4;
  const int srow = tid >> 3;       // 0..31
  const int scolb = (tid & 7) * 16;  // byte col in 128B row
  const int sk = (tid & 7) * 8;      // elem col

  float psum[2][4];
#pragma unroll
  for (int a = 0; a < 2; ++a)
#pragma unroll
    for (int b = 0; b < 4; ++b) psum[a][b] = 0.0f;

  for (int jt = 0; jt < JW; jt += 64) {
    const int jb = js * JW + jt;
    f32x4 acc1[2][2], acc2[2][2];
#pragma unroll
    for (int a = 0; a < 2; ++a)
#pragma unroll
      for (int b = 0; b < 2; ++b) {
        acc1[a][b] = (f32x4)(0.0f);
        acc2[a][b] = (f32x4)(0.0f);
      }
    for (int k0 = 0; k0 < DD; k0 += 64) {
      __syncthreads();
#pragma unroll
      for (int rr = 0; rr < 2; ++rr) {
        const int row = srow + rr * 32;
        const int sw = row * 128 + (scolb ^ ((row & 7) << 4));
        const float4 va = *(const float4*)(fnb + (size_t)(row0 + row) * DD + k0 + sk);
        const float4 vb1 = *(const float4*)(fob + (size_t)(jb + row) * DD + k0 + sk);
        const float4 vb2 = *(const float4*)(fnb + (size_t)(jb + row) * DD + k0 + sk);
        *(float4*)((char*)lA + sw) = va;
        *(float4*)((char*)lB1 + sw) = vb1;
        *(float4*)((char*)lB2 + sw) = vb2;
      }
      __syncthreads();
#pragma unroll
      for (int ks = 0; ks < 2; ++ks) {
        const int bc = ks * 64 + lkg * 16;
        bf16x8 a[2], b1[2], b2[2];
#pragma unroll
        for (int f = 0; f < 2; ++f) {
          const int ar = wr * 32 + f * 16 + lrow;
          a[f] = *(const bf16x8*)((const char*)lA + ar * 128 + (bc ^ ((ar & 7) << 4)));
          const int br = wc * 32 + f * 16 + lrow;
          b1[f] = *(const bf16x8*)((const char*)lB1 + br * 128 + (bc ^ ((br & 7) << 4)));
          b2[f] = *(const bf16x8*)((const char*)lB2 + br * 128 + (bc ^ ((br & 7) << 4)));
        }
#pragma unroll
        for (int fr = 0; fr < 2; ++fr)
#pragma unroll
          for (int fc = 0; fc < 2; ++fc) {
            acc1[fr][fc] = __builtin_amdgcn_mfma_f32_16x16x32_bf16(a[fr], b1[fc], acc1[fr][fc], 0, 0, 0);
            acc2[fr][fc] = __builtin_amdgcn_mfma_f32_16x16x32_bf16(a[fr], b2[fc], acc2[fr][fc], 0, 0, 0);
          }
      }
    }
    // epilogue: exp2 + accumulate (n2o diag kept: it stands in for the pos column;
    // n2n exact diagonal excluded here)
#pragma unroll
    for (int fr = 0; fr < 2; ++fr)
#pragma unroll
      for (int reg = 0; reg < 4; ++reg) {
        const int gr = row0 + wr * 32 + fr * 16 + lkg * 4 + reg;
        float s = psum[fr][reg];
#pragma unroll
        for (int fc = 0; fc < 2; ++fc) {
          const int gc = jb + wc * 32 + fc * 16 + lrow;
          s += __builtin_amdgcn_exp2f(fmaf(acc1[fr][fc][reg], CEXP, EOFF));
          const float p2 = __builtin_amdgcn_exp2f(fmaf(acc2[fr][fc][reg], CEXP, EOFF));
          s += (gr == gc) ? 0.0f : p2;
        }
        psum[fr][reg] = s;
      }
  }
  // reduce over the 16 lanes holding each row's columns, then write partial
#pragma unroll
  for (int fr = 0; fr < 2; ++fr)
#pragma unroll
    for (int reg = 0; reg < 4; ++reg) {
      float v = psum[fr][reg];
      v += __shfl_xor(v, 1);
      v += __shfl_xor(v, 2);
      v += __shfl_xor(v, 4);
      v += __shfl_xor(v, 8);
      if (lrow == 0) {
        const int gr = row0 + wr * 32 + fr * 16 + lkg * 4 + reg;
        partial[(size_t)gr * (NSLICE * 2) + js * 2 + wc] = v;
      }
    }
}

// ---------------- kernel 3: per-row same-label correction + log ----------------
__global__ __launch_bounds__(64) void k_final(const u16* __restrict__ fnb,
                                              const u16* __restrict__ fob,
                                              const int* __restrict__ tgt,
                                              const float* __restrict__ partial,
                                              const float* __restrict__ pos,
                                              float* __restrict__ rowloss) {
  const int i = blockIdx.x;
  const int lane = threadIdx.x;
  float v = 0.0f;
  if (lane < NSLICE * 2) v = partial[(size_t)i * (NSLICE * 2) + lane];
  const int ti = tgt[i];
  for (int j = lane; j < BB; j += 64) {
    if (j != i && tgt[j] == ti) {
      const u16* xi = fnb + (size_t)i * DD;
      const u16* yo = fob + (size_t)j * DD;
      const u16* yn = fnb + (size_t)j * DD;
      float d1 = 0.0f, d2 = 0.0f;
      for (int k = 0; k < DD; k += 4) {
        const ushort4 a = *(const ushort4*)(xi + k);
        const ushort4 b = *(const ushort4*)(yo + k);
        const ushort4 c = *(const ushort4*)(yn + k);
        const float ax = bfu(a.x), ay = bfu(a.y), az = bfu(a.z), aw = bfu(a.w);
        d1 += ax * bfu(b.x) + ay * bfu(b.y) + az * bfu(b.z) + aw * bfu(b.w);
        d2 += ax * bfu(c.x) + ay * bfu(c.y) + az * bfu(c.z) + aw * bfu(c.w);
      }
      v -= __builtin_amdgcn_exp2f(fmaf(d1, CEXP, EOFF));
      v -= __builtin_amdgcn_exp2f(fmaf(d2, CEXP, EOFF));
    }
  }
  v = wave_sum(v);
  if (lane == 0) {
    rowloss[i] = LSE_BASE + __builtin_amdgcn_logf(v) * LN2 - 100.0f * pos[i];
  }
}

// ---------------- kernel 4: mean ----------------
__global__ __launch_bounds__(256) void k_mean(const float* __restrict__ rl,
                                              float* __restrict__ out) {
  const int t = threadIdx.x;
  float s = 0.0f;
  for (int i = t; i < BB; i += 256) s += rl[i];
  s = wave_sum(s);
  __shared__ float red[4];
  if ((t & 63) == 0) red[t >> 6] = s;
  __syncthreads();
  if (t == 0) out[0] = (red[0] + red[1] + red[2] + red[3]) * (1.0f / (float)BB);
}

extern "C" void kernel_launch(void* const* d_in, const int* in_sizes, int n_in,
                              void* d_out, int out_size, void* d_ws, size_t ws_size,
                              hipStream_t stream) {
  const float* feat = (const float*)d_in[0];
  const float* feat_old = (const float*)d_in[1];
  const int* targets = (const int*)d_in[2];
  float* out = (float*)d_out;
  char* ws = (char*)d_ws;

  u16* fnb = (u16*)ws;                                   // 4 MB
  u16* fob = (u16*)(ws + 4u * 1024 * 1024);              // 4 MB
  float* pos = (float*)(ws + 8u * 1024 * 1024);          // 16 KB
  float* partial = (float*)(ws + 8u * 1024 * 1024 + 16 * 1024);   // 256 KB
  float* rowloss = (float*)(ws + 8u * 1024 * 1024 + 272 * 1024);  // 16 KB

  k_norm<<<BB, 64, 0, stream>>>(feat, feat_old, fnb, fob, pos);
  dim3 g2(BB / 64, NSLICE);
  k_fused<<<g2, 256, 0, stream>>>(fnb, fob, partial);
  k_final<<<BB, 64, 0, stream>>>(fnb, fob, targets, partial, pos, rowloss);
  k_mean<<<1, 256, 0, stream>>>(rowloss, out);
}

// Round 2
// 80.138 us; speedup vs baseline: 3.0662x; 3.0662x over previous
//
#include <hip/hip_runtime.h>
#include <hip/hip_bf16.h>

#define BB 4096
#define DD 512
#define NSLICE 8
#define JW (BB / NSLICE)  // 512

typedef unsigned short u16;
typedef unsigned int u32;

using f32x4 = __attribute__((ext_vector_type(4))) float;
using bf16x8 = __attribute__((ext_vector_type(8))) short;

// exp scaling: p = exp2((s-1)*100*log2e + 64)  -> all normal-range for s in [-0.44, 1]
// lse = 100 - 64*ln2 + ln(sum p)
constexpr float CEXP = 144.26950408889634f;          // 100 * log2(e)
constexpr float EOFF = 64.0f - 144.26950408889634f;  // bias - CEXP
constexpr float LN2 = 0.6931471805599453f;
constexpr float LSE_BASE = 100.0f - 64.0f * 0.6931471805599453f;  // 55.63858...

__device__ __forceinline__ float wave_sum(float v) {
#pragma unroll
  for (int m = 1; m < 64; m <<= 1) v += __shfl_xor(v, m);
  return v;
}

__device__ __forceinline__ u16 f2bf(float f) {
  __hip_bfloat16 h = __float2bfloat16(f);
  return __builtin_bit_cast(u16, h);
}

// ---------------- kernel 1: row L2-normalize (fp32) -> bf16, plus fp32 pos ----------------
__global__ __launch_bounds__(64) void k_norm(const float* __restrict__ feat,
                                             const float* __restrict__ feat_old,
                                             u16* __restrict__ fnb, u16* __restrict__ fob,
                                             float* __restrict__ pos) {
  const int i = blockIdx.x;
  const int t = threadIdx.x;
  const float4 x0 = *(const float4*)(feat + (size_t)i * DD + t * 4);
  const float4 x1 = *(const float4*)(feat + (size_t)i * DD + 256 + t * 4);
  const float4 y0 = *(const float4*)(feat_old + (size_t)i * DD + t * 4);
  const float4 y1 = *(const float4*)(feat_old + (size_t)i * DD + 256 + t * 4);
  float sx = x0.x * x0.x + x0.y * x0.y + x0.z * x0.z + x0.w * x0.w +
             x1.x * x1.x + x1.y * x1.y + x1.z * x1.z + x1.w * x1.w;
  float sy = y0.x * y0.x + y0.y * y0.y + y0.z * y0.z + y0.w * y0.w +
             y1.x * y1.x + y1.y * y1.y + y1.z * y1.z + y1.w * y1.w;
  float sxy = x0.x * y0.x + x0.y * y0.y + x0.z * y0.z + x0.w * y0.w +
              x1.x * y1.x + x1.y * y1.y + x1.z * y1.z + x1.w * y1.w;
  sx = wave_sum(sx);
  sy = wave_sum(sy);
  sxy = wave_sum(sxy);
  const float inx = 1.0f / fmaxf(sqrtf(sx), 1e-12f);
  const float iny = 1.0f / fmaxf(sqrtf(sy), 1e-12f);
  ushort4 ox0, ox1, oy0, oy1;
  ox0.x = f2bf(x0.x * inx); ox0.y = f2bf(x0.y * inx);
  ox0.z = f2bf(x0.z * inx); ox0.w = f2bf(x0.w * inx);
  ox1.x = f2bf(x1.x * inx); ox1.y = f2bf(x1.y * inx);
  ox1.z = f2bf(x1.z * inx); ox1.w = f2bf(x1.w * inx);
  oy0.x = f2bf(y0.x * iny); oy0.y = f2bf(y0.y * iny);
  oy0.z = f2bf(y0.z * iny); oy0.w = f2bf(y0.w * iny);
  oy1.x = f2bf(y1.x * iny); oy1.y = f2bf(y1.y * iny);
  oy1.z = f2bf(y1.z * iny); oy1.w = f2bf(y1.w * iny);
  *(ushort4*)(fnb + (size_t)i * DD + t * 4) = ox0;
  *(ushort4*)(fnb + (size_t)i * DD + 256 + t * 4) = ox1;
  *(ushort4*)(fob + (size_t)i * DD + t * 4) = oy0;
  *(ushort4*)(fob + (size_t)i * DD + 256 + t * 4) = oy1;
  if (t == 0) pos[i] = sxy * inx * iny;
}

// ---------------- kernel 2: fused dual-GEMM + masked exp2 partial sums ----------------
// grid (64 row-tiles, NSLICE j-slices), 256 threads (4 waves, 2x2 of 32x32 each)
// masking done inline via targets: same-label pairs never enter the sum.
__global__ __launch_bounds__(256) void k_fused(const u16* __restrict__ fnb,
                                               const u16* __restrict__ fob,
                                               const int* __restrict__ tgt,
                                               float* __restrict__ partial) {
  __shared__ __align__(16) u16 lA[64 * 64];
  __shared__ __align__(16) u16 lB1[64 * 64];
  __shared__ __align__(16) u16 lB2[64 * 64];
  const int tid = threadIdx.x;
  const int lane = tid & 63;
  const int wid = tid >> 6;
  const int wr = wid >> 1, wc = wid & 1;
  const int row0 = blockIdx.x * 64;
  const int js = blockIdx.y;
  const int lrow = lane & 15;
  const int lkg = lane >> 4;
  const int srow = tid >> 3;         // 0..31
  const int scolb = (tid & 7) * 16;  // byte col in 128B row
  const int sk = (tid & 7) * 8;      // elem col

  // row labels for this lane's 8 output rows (fixed for whole kernel)
  int tr[2][4];
#pragma unroll
  for (int fr = 0; fr < 2; ++fr)
#pragma unroll
    for (int reg = 0; reg < 4; ++reg)
      tr[fr][reg] = tgt[row0 + wr * 32 + fr * 16 + lkg * 4 + reg];

  float psum[2][4];
#pragma unroll
  for (int a = 0; a < 2; ++a)
#pragma unroll
    for (int b = 0; b < 4; ++b) psum[a][b] = 0.0f;

  for (int jt = 0; jt < JW; jt += 64) {
    const int jb = js * JW + jt;
    f32x4 acc1[2][2], acc2[2][2];
#pragma unroll
    for (int a = 0; a < 2; ++a)
#pragma unroll
      for (int b = 0; b < 2; ++b) {
        acc1[a][b] = (f32x4)(0.0f);
        acc2[a][b] = (f32x4)(0.0f);
      }
    for (int k0 = 0; k0 < DD; k0 += 64) {
      __syncthreads();
#pragma unroll
      for (int rr = 0; rr < 2; ++rr) {
        const int row = srow + rr * 32;
        const int sw = row * 128 + (scolb ^ ((row & 7) << 4));
        const float4 va = *(const float4*)(fnb + (size_t)(row0 + row) * DD + k0 + sk);
        const float4 vb1 = *(const float4*)(fob + (size_t)(jb + row) * DD + k0 + sk);
        const float4 vb2 = *(const float4*)(fnb + (size_t)(jb + row) * DD + k0 + sk);
        *(float4*)((char*)lA + sw) = va;
        *(float4*)((char*)lB1 + sw) = vb1;
        *(float4*)((char*)lB2 + sw) = vb2;
      }
      __syncthreads();
#pragma unroll
      for (int ks = 0; ks < 2; ++ks) {
        const int bc = ks * 64 + lkg * 16;
        bf16x8 a[2], b1[2], b2[2];
#pragma unroll
        for (int f = 0; f < 2; ++f) {
          const int ar = wr * 32 + f * 16 + lrow;
          a[f] = *(const bf16x8*)((const char*)lA + ar * 128 + (bc ^ ((ar & 7) << 4)));
          const int br = wc * 32 + f * 16 + lrow;
          b1[f] = *(const bf16x8*)((const char*)lB1 + br * 128 + (bc ^ ((br & 7) << 4)));
          b2[f] = *(const bf16x8*)((const char*)lB2 + br * 128 + (bc ^ ((br & 7) << 4)));
        }
#pragma unroll
        for (int fr = 0; fr < 2; ++fr)
#pragma unroll
          for (int fc = 0; fc < 2; ++fc) {
            acc1[fr][fc] = __builtin_amdgcn_mfma_f32_16x16x32_bf16(a[fr], b1[fc], acc1[fr][fc], 0, 0, 0);
            acc2[fr][fc] = __builtin_amdgcn_mfma_f32_16x16x32_bf16(a[fr], b2[fc], acc2[fr][fc], 0, 0, 0);
          }
      }
    }
    // epilogue: exp2 + masked accumulate.
    //  n2o: keep diagonal (stands in for the explicit pos column), drop same-label off-diag
    //  n2n: drop all same-label (diagonal included)
    int tc[2];
#pragma unroll
    for (int fc = 0; fc < 2; ++fc) tc[fc] = tgt[jb + wc * 32 + fc * 16 + lrow];
#pragma unroll
    for (int fr = 0; fr < 2; ++fr)
#pragma unroll
      for (int reg = 0; reg < 4; ++reg) {
        const int gr = row0 + wr * 32 + fr * 16 + lkg * 4 + reg;
        float s = psum[fr][reg];
#pragma unroll
        for (int fc = 0; fc < 2; ++fc) {
          const int gc = jb + wc * 32 + fc * 16 + lrow;
          const bool diff = (tr[fr][reg] != tc[fc]);
          const float p1 = __builtin_amdgcn_exp2f(fmaf(acc1[fr][fc][reg], CEXP, EOFF));
          const float p2 = __builtin_amdgcn_exp2f(fmaf(acc2[fr][fc][reg], CEXP, EOFF));
          s += (diff || gr == gc) ? p1 : 0.0f;
          s += diff ? p2 : 0.0f;
        }
        psum[fr][reg] = s;
      }
  }
  // reduce over the 16 lanes holding each row's columns, then write partial
#pragma unroll
  for (int fr = 0; fr < 2; ++fr)
#pragma unroll
    for (int reg = 0; reg < 4; ++reg) {
      float v = psum[fr][reg];
      v += __shfl_xor(v, 1);
      v += __shfl_xor(v, 2);
      v += __shfl_xor(v, 4);
      v += __shfl_xor(v, 8);
      if (lrow == 0) {
        const int gr = row0 + wr * 32 + fr * 16 + lkg * 4 + reg;
        partial[(size_t)gr * (NSLICE * 2) + js * 2 + wc] = v;
      }
    }
}

// ---------------- kernel 3: per-row finalize + mean (single block) ----------------
__global__ __launch_bounds__(1024) void k_finalmean(const float* __restrict__ partial,
                                                    const float* __restrict__ pos,
                                                    float* __restrict__ out) {
  const int t = threadIdx.x;
  float s = 0.0f;
#pragma unroll
  for (int r = 0; r < 4; ++r) {
    const int i = t * 4 + r;
    const float4* p = (const float4*)(partial + (size_t)i * 16);
    const float4 a = p[0], b = p[1], c = p[2], d = p[3];
    const float v = ((a.x + a.y) + (a.z + a.w)) + ((b.x + b.y) + (b.z + b.w)) +
                    ((c.x + c.y) + (c.z + c.w)) + ((d.x + d.y) + (d.z + d.w));
    s += LSE_BASE + __builtin_amdgcn_logf(v) * LN2 - 100.0f * pos[i];
  }
  s = wave_sum(s);
  __shared__ float red[16];
  if ((t & 63) == 0) red[t >> 6] = s;
  __syncthreads();
  if (t == 0) {
    float tot = 0.0f;
#pragma unroll
    for (int w = 0; w < 16; ++w) tot += red[w];
    out[0] = tot * (1.0f / (float)BB);
  }
}

extern "C" void kernel_launch(void* const* d_in, const int* in_sizes, int n_in,
                              void* d_out, int out_size, void* d_ws, size_t ws_size,
                              hipStream_t stream) {
  const float* feat = (const float*)d_in[0];
  const float* feat_old = (const float*)d_in[1];
  const int* targets = (const int*)d_in[2];
  float* out = (float*)d_out;
  char* ws = (char*)d_ws;

  u16* fnb = (u16*)ws;                                            // 4 MB
  u16* fob = (u16*)(ws + 4u * 1024 * 1024);                       // 4 MB
  float* pos = (float*)(ws + 8u * 1024 * 1024);                   // 16 KB
  float* partial = (float*)(ws + 8u * 1024 * 1024 + 16 * 1024);   // 256 KB

  k_norm<<<BB, 64, 0, stream>>>(feat, feat_old, fnb, fob, pos);
  dim3 g2(BB / 64, NSLICE);
  k_fused<<<g2, 256, 0, stream>>>(fnb, fob, targets, partial);
  k_finalmean<<<1, 1024, 0, stream>>>(partial, pos, out);
}

// Round 3
// 73.856 us; speedup vs baseline: 3.3270x; 1.0851x over previous
//
#include <hip/hip_runtime.h>
#include <hip/hip_bf16.h>

#define BB 4096
#define DD 512

typedef unsigned short u16;
typedef unsigned int u32;

using f32x4 = __attribute__((ext_vector_type(4))) float;
using bf16x8 = __attribute__((ext_vector_type(8))) short;

// exp scaling: p = exp2((s-1)*100*log2e + 64)  -> all normal-range for s in [-0.44, 1]
// lse = 100 - 64*ln2 + ln(sum p)
constexpr float CEXP = 144.26950408889634f;          // 100 * log2(e)
constexpr float EOFF = 64.0f - 144.26950408889634f;  // bias - CEXP
constexpr float LN2 = 0.6931471805599453f;
constexpr float LSE_BASE = 100.0f - 64.0f * 0.6931471805599453f;

__device__ __forceinline__ float wave_sum(float v) {
#pragma unroll
  for (int m = 1; m < 64; m <<= 1) v += __shfl_xor(v, m);
  return v;
}

__device__ __forceinline__ u16 f2bf(float f) {
  __hip_bfloat16 h = __float2bfloat16(f);
  return __builtin_bit_cast(u16, h);
}

// async global->LDS, 16B per lane. LDS dest is wave-uniform base + lane*16.
__device__ __forceinline__ void gload16(const u16* g, const u16* l) {
  __builtin_amdgcn_global_load_lds(
      (const __attribute__((address_space(1))) void*)g,
      (__attribute__((address_space(3))) void*)(const_cast<u16*>(l)), 16, 0, 0);
}

// ---------------- kernel 1: row L2-normalize (fp32) -> bf16, plus fp32 pos ----------------
// 4 rows per 256-thread block (1 wave / row)
__global__ __launch_bounds__(256) void k_norm(const float* __restrict__ feat,
                                              const float* __restrict__ feat_old,
                                              u16* __restrict__ fnb, u16* __restrict__ fob,
                                              float* __restrict__ pos) {
  const int i = blockIdx.x * 4 + (threadIdx.x >> 6);
  const int t = threadIdx.x & 63;
  const float4 x0 = *(const float4*)(feat + (size_t)i * DD + t * 4);
  const float4 x1 = *(const float4*)(feat + (size_t)i * DD + 256 + t * 4);
  const float4 y0 = *(const float4*)(feat_old + (size_t)i * DD + t * 4);
  const float4 y1 = *(const float4*)(feat_old + (size_t)i * DD + 256 + t * 4);
  float sx = x0.x * x0.x + x0.y * x0.y + x0.z * x0.z + x0.w * x0.w +
             x1.x * x1.x + x1.y * x1.y + x1.z * x1.z + x1.w * x1.w;
  float sy = y0.x * y0.x + y0.y * y0.y + y0.z * y0.z + y0.w * y0.w +
             y1.x * y1.x + y1.y * y1.y + y1.z * y1.z + y1.w * y1.w;
  float sxy = x0.x * y0.x + x0.y * y0.y + x0.z * y0.z + x0.w * y0.w +
              x1.x * y1.x + x1.y * y1.y + x1.z * y1.z + x1.w * y1.w;
  sx = wave_sum(sx);
  sy = wave_sum(sy);
  sxy = wave_sum(sxy);
  const float inx = 1.0f / fmaxf(sqrtf(sx), 1e-12f);
  const float iny = 1.0f / fmaxf(sqrtf(sy), 1e-12f);
  ushort4 ox0, ox1, oy0, oy1;
  ox0.x = f2bf(x0.x * inx); ox0.y = f2bf(x0.y * inx);
  ox0.z = f2bf(x0.z * inx); ox0.w = f2bf(x0.w * inx);
  ox1.x = f2bf(x1.x * inx); ox1.y = f2bf(x1.y * inx);
  ox1.z = f2bf(x1.z * inx); ox1.w = f2bf(x1.w * inx);
  oy0.x = f2bf(y0.x * iny); oy0.y = f2bf(y0.y * iny);
  oy0.z = f2bf(y0.z * iny); oy0.w = f2bf(y0.w * iny);
  oy1.x = f2bf(y1.x * iny); oy1.y = f2bf(y1.y * iny);
  oy1.z = f2bf(y1.z * iny); oy1.w = f2bf(y1.w * iny);
  *(ushort4*)(fnb + (size_t)i * DD + t * 4) = ox0;
  *(ushort4*)(fnb + (size_t)i * DD + 256 + t * 4) = ox1;
  *(ushort4*)(fob + (size_t)i * DD + t * 4) = oy0;
  *(ushort4*)(fob + (size_t)i * DD + 256 + t * 4) = oy1;
  if (t == 0) pos[i] = sxy * inx * iny;
}

// ---------------- kernel 2: fused dual-GEMM + masked exp2 row partials ----------------
// 1024 blocks (XCD-swizzled 32x32 tiles of 128x[128|128]), 512 threads = 8 waves (2Mx4N).
// Staging via global_load_lds w16 with pre-swizzled global source (linear LDS dest).
__global__ __launch_bounds__(512, 4) void k_fused(const u16* __restrict__ fnb,
                                                  const u16* __restrict__ fob,
                                                  const int* __restrict__ tgt,
                                                  float* __restrict__ partial) {
  __shared__ __align__(16) u16 lA[128 * 64];
  __shared__ __align__(16) u16 lB1[128 * 64];
  __shared__ __align__(16) u16 lB2[128 * 64];
  __shared__ float rsumL[2][4][64];

  const int tid = threadIdx.x;
  const int lane = tid & 63;
  const int wid = tid >> 6;  // 0..7
  const int wr = wid >> 2;   // 0..1  (M half)
  const int wc = wid & 3;    // 0..3  (N quarter; 0,1->B1  2,3->B2)
  const int lrow = lane & 15;
  const int lkg = lane >> 4;

  // XCD-aware bijective swizzle (1024 % 8 == 0): each XCD gets 4 contiguous M-rows
  const int flat = blockIdx.x;
  const int swz = (flat & 7) * 128 + (flat >> 3);
  const int mt = swz >> 5, nt = swz & 31;
  const int row0 = mt * 128, jb = nt * 128;

  // staging geometry: chunk = 8 rows x 128B; wave w stages chunks {2w, 2w+1} of each tile
  const int cr = lane >> 3;              // row within chunk
  const int ce = 8 * ((lane & 7) ^ cr);  // pre-swizzled col (elems)
  const int ch0 = wid * 2;

  f32x4 acc[4][4];
#pragma unroll
  for (int a = 0; a < 4; ++a)
#pragma unroll
    for (int b = 0; b < 4; ++b) acc[a][b] = (f32x4)(0.0f);

  for (int k0 = 0; k0 < DD; k0 += 64) {
    __syncthreads();  // previous compute done reading LDS
#pragma unroll
    for (int i = 0; i < 2; ++i) {
      const int ch = ch0 + i;
      const int r = ch * 8 + cr;
      gload16(fnb + (size_t)(row0 + r) * DD + k0 + ce, lA + ch * 512);
      gload16(fob + (size_t)(jb + r) * DD + k0 + ce, lB1 + ch * 512);
      gload16(fnb + (size_t)(jb + r) * DD + k0 + ce, lB2 + ch * 512);
    }
    __syncthreads();  // vmcnt drained -> staged tile visible
    const u16* lB = (wc < 2) ? lB1 : lB2;
#pragma unroll
    for (int ks = 0; ks < 2; ++ks) {
      const int bc = ks * 64 + lkg * 16;  // byte col in 128B row
      bf16x8 av[4], bv[4];
#pragma unroll
      for (int f = 0; f < 4; ++f) {
        const int ar = wr * 64 + f * 16 + lrow;
        av[f] = *(const bf16x8*)((const char*)lA + ar * 128 + (bc ^ ((ar & 7) << 4)));
        const int br = (wc & 1) * 64 + f * 16 + lrow;
        bv[f] = *(const bf16x8*)((const char*)lB + br * 128 + (bc ^ ((br & 7) << 4)));
      }
#pragma unroll
      for (int fr = 0; fr < 4; ++fr)
#pragma unroll
        for (int fc = 0; fc < 4; ++fc)
          acc[fr][fc] = __builtin_amdgcn_mfma_f32_16x16x32_bf16(av[fr], bv[fc], acc[fr][fc], 0, 0, 0);
    }
  }

  // epilogue: masked exp2, reduce cols within wave, stash per-row sums in LDS
  const bool isN2O = (wc < 2);
  int tc[4];
#pragma unroll
  for (int fc = 0; fc < 4; ++fc) tc[fc] = tgt[jb + (wc & 1) * 64 + fc * 16 + lrow];
#pragma unroll
  for (int fr = 0; fr < 4; ++fr) {
#pragma unroll
    for (int reg = 0; reg < 4; ++reg) {
      const int gr = row0 + wr * 64 + fr * 16 + lkg * 4 + reg;
      const int trv = tgt[gr];
      float s = 0.0f;
#pragma unroll
      for (int fc = 0; fc < 4; ++fc) {
        const int gc = jb + (wc & 1) * 64 + fc * 16 + lrow;
        const float p = __builtin_amdgcn_exp2f(fmaf(acc[fr][fc][reg], CEXP, EOFF));
        // n2o: keep diagonal (stands in for the explicit pos column), drop same-label
        // n2n: drop all same-label (diagonal auto-dropped, labels equal)
        const bool keep = (trv != tc[fc]) || (isN2O && gr == gc);
        s += keep ? p : 0.0f;
      }
      s += __shfl_xor(s, 1);
      s += __shfl_xor(s, 2);
      s += __shfl_xor(s, 4);
      s += __shfl_xor(s, 8);
      if (lrow == 0) rsumL[wr][wc][fr * 16 + lkg * 4 + reg] = s;
    }
  }
  __syncthreads();
  if (tid < 128) {
    const int wrg = tid >> 6, rl = tid & 63;
    const float v = rsumL[wrg][0][rl] + rsumL[wrg][1][rl] + rsumL[wrg][2][rl] + rsumL[wrg][3][rl];
    partial[(size_t)(row0 + wrg * 64 + rl) * 32 + nt] = v;
  }
}

// ---------------- kernel 3: per-row finalize + mean (single block) ----------------
__global__ __launch_bounds__(1024) void k_finalmean(const float* __restrict__ partial,
                                                    const float* __restrict__ pos,
                                                    float* __restrict__ out) {
  const int t = threadIdx.x;
  float s = 0.0f;
#pragma unroll
  for (int r = 0; r < 4; ++r) {
    const int i = t * 4 + r;
    const float4* p = (const float4*)(partial + (size_t)i * 32);
    float v = 0.0f;
#pragma unroll
    for (int q = 0; q < 8; ++q) {
      const float4 a = p[q];
      v += (a.x + a.y) + (a.z + a.w);
    }
    s += LSE_BASE + __builtin_amdgcn_logf(v) * LN2 - 100.0f * pos[i];
  }
  s = wave_sum(s);
  __shared__ float red[16];
  if ((t & 63) == 0) red[t >> 6] = s;
  __syncthreads();
  if (t == 0) {
    float tot = 0.0f;
#pragma unroll
    for (int w = 0; w < 16; ++w) tot += red[w];
    out[0] = tot * (1.0f / (float)BB);
  }
}

extern "C" void kernel_launch(void* const* d_in, const int* in_sizes, int n_in,
                              void* d_out, int out_size, void* d_ws, size_t ws_size,
                              hipStream_t stream) {
  const float* feat = (const float*)d_in[0];
  const float* feat_old = (const float*)d_in[1];
  const int* targets = (const int*)d_in[2];
  float* out = (float*)d_out;
  char* ws = (char*)d_ws;

  u16* fnb = (u16*)ws;                                           // 4 MB
  u16* fob = (u16*)(ws + 4u * 1024 * 1024);                      // 4 MB
  float* pos = (float*)(ws + 8u * 1024 * 1024);                  // 16 KB
  float* partial = (float*)(ws + 8u * 1024 * 1024 + 16 * 1024);  // 512 KB

  k_norm<<<BB / 4, 256, 0, stream>>>(feat, feat_old, fnb, fob, pos);
  k_fused<<<1024, 512, 0, stream>>>(fnb, fob, targets, partial);
  k_finalmean<<<1, 1024, 0, stream>>>(partial, pos, out);
}

// Round 4
// 58.188 us; speedup vs baseline: 4.2228x; 1.2693x over previous
//
#include <hip/hip_runtime.h>
#include <hip/hip_bf16.h>

#define BB 4096
#define DD 512

typedef unsigned short u16;
typedef unsigned int u32;

using f32x4 = __attribute__((ext_vector_type(4))) float;
using bf16x8 = __attribute__((ext_vector_type(8))) short;

// exp scaling: p = exp2((s-1)*100*log2e + 64)  -> all normal-range for s in [-0.44, 1]
// lse = 100 - 64*ln2 + ln(sum p)
constexpr float CEXP = 144.26950408889634f;          // 100 * log2(e)
constexpr float EOFF = 64.0f - 144.26950408889634f;  // bias - CEXP
constexpr float LN2 = 0.6931471805599453f;
constexpr float LSE_BASE = 100.0f - 64.0f * 0.6931471805599453f;

__device__ __forceinline__ float wave_sum(float v) {
#pragma unroll
  for (int m = 1; m < 64; m <<= 1) v += __shfl_xor(v, m);
  return v;
}

__device__ __forceinline__ u16 f2bf(float f) {
  __hip_bfloat16 h = __float2bfloat16(f);
  return __builtin_bit_cast(u16, h);
}

// async global->LDS, 16B per lane. LDS dest is wave-uniform base + lane*16.
__device__ __forceinline__ void gload16(const u16* g, const u16* l) {
  __builtin_amdgcn_global_load_lds(
      (const __attribute__((address_space(1))) void*)g,
      (__attribute__((address_space(3))) void*)(const_cast<u16*>(l)), 16, 0, 0);
}

// raw barrier (no vmcnt(0)/lgkmcnt(0) drain) + compiler memory fences so LDS
// reads/writes can't be moved across it
__device__ __forceinline__ void barrier_raw() {
  asm volatile("" ::: "memory");
  __builtin_amdgcn_s_barrier();
  asm volatile("" ::: "memory");
}

// ---------------- kernel 1: row L2-normalize (fp32) -> bf16, plus fp32 pos ----------------
__global__ __launch_bounds__(256) void k_norm(const float* __restrict__ feat,
                                              const float* __restrict__ feat_old,
                                              u16* __restrict__ fnb, u16* __restrict__ fob,
                                              float* __restrict__ pos) {
  const int i = blockIdx.x * 4 + (threadIdx.x >> 6);
  const int t = threadIdx.x & 63;
  const float4 x0 = *(const float4*)(feat + (size_t)i * DD + t * 4);
  const float4 x1 = *(const float4*)(feat + (size_t)i * DD + 256 + t * 4);
  const float4 y0 = *(const float4*)(feat_old + (size_t)i * DD + t * 4);
  const float4 y1 = *(const float4*)(feat_old + (size_t)i * DD + 256 + t * 4);
  float sx = x0.x * x0.x + x0.y * x0.y + x0.z * x0.z + x0.w * x0.w +
             x1.x * x1.x + x1.y * x1.y + x1.z * x1.z + x1.w * x1.w;
  float sy = y0.x * y0.x + y0.y * y0.y + y0.z * y0.z + y0.w * y0.w +
             y1.x * y1.x + y1.y * y1.y + y1.z * y1.z + y1.w * y1.w;
  float sxy = x0.x * y0.x + x0.y * y0.y + x0.z * y0.z + x0.w * y0.w +
              x1.x * y1.x + x1.y * y1.y + x1.z * y1.z + x1.w * y1.w;
  sx = wave_sum(sx);
  sy = wave_sum(sy);
  sxy = wave_sum(sxy);
  const float inx = 1.0f / fmaxf(sqrtf(sx), 1e-12f);
  const float iny = 1.0f / fmaxf(sqrtf(sy), 1e-12f);
  ushort4 ox0, ox1, oy0, oy1;
  ox0.x = f2bf(x0.x * inx); ox0.y = f2bf(x0.y * inx);
  ox0.z = f2bf(x0.z * inx); ox0.w = f2bf(x0.w * inx);
  ox1.x = f2bf(x1.x * inx); ox1.y = f2bf(x1.y * inx);
  ox1.z = f2bf(x1.z * inx); ox1.w = f2bf(x1.w * inx);
  oy0.x = f2bf(y0.x * iny); oy0.y = f2bf(y0.y * iny);
  oy0.z = f2bf(y0.z * iny); oy0.w = f2bf(y0.w * iny);
  oy1.x = f2bf(y1.x * iny); oy1.y = f2bf(y1.y * iny);
  oy1.z = f2bf(y1.z * iny); oy1.w = f2bf(y1.w * iny);
  *(ushort4*)(fnb + (size_t)i * DD + t * 4) = ox0;
  *(ushort4*)(fnb + (size_t)i * DD + 256 + t * 4) = ox1;
  *(ushort4*)(fob + (size_t)i * DD + t * 4) = oy0;
  *(ushort4*)(fob + (size_t)i * DD + 256 + t * 4) = oy1;
  if (t == 0) pos[i] = sxy * inx * iny;
}

// ---------------- kernel 2: fused dual-GEMM, counted-vmcnt pipeline ----------------
// 512 blocks = 16 mt x 32 nt (XCD-swizzled). 512 threads = 8 waves: wr = wid&3
// (64-row M quarter), sel = wid>>2 (B1=old / B2=new). Tile: A 256xK, B 128xK each.
// LDS double-buffered (128 KB); staging via global_load_lds w16 with pre-swizzled
// global source; vmcnt never drains to 0 in the main loop.
__global__ __launch_bounds__(512, 2) void k_fused(const u16* __restrict__ fnb,
                                                  const u16* __restrict__ fob,
                                                  const int* __restrict__ tgt,
                                                  float* __restrict__ partial) {
  __shared__ __align__(16) u16 lA[2 * 256 * 64];   // 64 KB
  __shared__ __align__(16) u16 lB1[2 * 128 * 64];  // 32 KB
  __shared__ __align__(16) u16 lB2[2 * 128 * 64];  // 32 KB

  const int tid = threadIdx.x;
  const int lane = tid & 63;
  const int wid = tid >> 6;   // 0..7
  const int wr = wid & 3;     // M quarter
  const int sel = wid >> 2;   // 0: B1(old)  1: B2(new)
  const int lrow = lane & 15;
  const int lkg = lane >> 4;

  // XCD-aware bijective swizzle (512 % 8 == 0): XCD x gets mt {2x, 2x+1}
  const int flat = blockIdx.x;
  const int swz = (flat & 7) * 64 + (flat >> 3);
  const int mt = swz >> 5, nt = swz & 31;
  const int row0 = mt * 256, jb = nt * 128;

  // staging: chunk = 8 rows x 128B = 64 lanes x 16B. source col pre-swizzled so
  // the linear LDS write lands in XOR-swizzled position.
  const int cr = lane >> 3;              // row within chunk
  const int ce = 8 * ((lane & 7) ^ cr);  // pre-swizzled col (elems)

  f32x4 acc[4][8];
#pragma unroll
  for (int a = 0; a < 4; ++a)
#pragma unroll
    for (int b = 0; b < 8; ++b) acc[a][b] = (f32x4)(0.0f);

  // ---- staging helpers: 4 A-loads (phase A) / 4 B-loads (phase B) per wave ----
  auto stageA = [&](u16* dst, int kk) {
#pragma unroll
    for (int i = 0; i < 4; ++i) {
      const int c = wid * 4 + i;  // 32 chunks cover 256 A rows
      gload16(fnb + (size_t)(row0 + c * 8 + cr) * DD + kk + ce, dst + c * 512);
    }
  };
  auto stageB = [&](u16* d1, u16* d2, int kk) {
#pragma unroll
    for (int i = 0; i < 2; ++i) {
      const int c = wid * 2 + i;  // 16 chunks cover 128 B rows
      gload16(fob + (size_t)(jb + c * 8 + cr) * DD + kk + ce, d1 + c * 512);
      gload16(fnb + (size_t)(jb + c * 8 + cr) * DD + kk + ce, d2 + c * 512);
    }
  };

  // prologue: stage tile 0 into buffer 0 (8 loads in flight)
  stageA(lA, 0);
  stageB(lB1, lB2, 0);

  for (int t = 0; t < 8; ++t) {
    const int cur = t & 1, nxt = cur ^ 1;
    const char* cA = (const char*)(lA + cur * (256 * 64));
    const char* cB = (const char*)((sel ? lB2 : lB1) + cur * (128 * 64));

    // ---- phase A: prefetch next A, wait current tile, compute ks=0 ----
    if (t < 7) {
      stageA(lA + nxt * (256 * 64), (t + 1) * 64);
      asm volatile("s_waitcnt vmcnt(4)" ::: "memory");  // tile-t's 8 done; 4 new in flight
    } else {
      asm volatile("s_waitcnt vmcnt(0)" ::: "memory");  // last tile: drain ok
    }
    barrier_raw();  // all waves' tile-t loads landed
#pragma unroll
    for (int ks = 0; ks < 2; ++ks) {
      // ---- phase B prefetch goes out between the two MFMA clusters ----
      if (ks == 1 && t < 7)
        stageB(lB1 + nxt * (128 * 64), lB2 + nxt * (128 * 64), (t + 1) * 64);
      const int bc = ks * 64 + lkg * 16;
      bf16x8 av[4], bv[8];
#pragma unroll
      for (int f = 0; f < 4; ++f) {
        const int ar = wr * 64 + f * 16 + lrow;
        av[f] = *(const bf16x8*)(cA + ar * 128 + (bc ^ ((ar & 7) << 4)));
      }
#pragma unroll
      for (int f = 0; f < 8; ++f) {
        const int br = f * 16 + lrow;
        bv[f] = *(const bf16x8*)(cB + br * 128 + (bc ^ ((br & 7) << 4)));
      }
      __builtin_amdgcn_s_setprio(1);
#pragma unroll
      for (int fr = 0; fr < 4; ++fr)
#pragma unroll
        for (int fc = 0; fc < 8; ++fc)
          acc[fr][fc] = __builtin_amdgcn_mfma_f32_16x16x32_bf16(av[fr], bv[fc], acc[fr][fc], 0, 0, 0);
      __builtin_amdgcn_s_setprio(0);
    }
    barrier_raw();  // all waves done reading buf[cur] before t+1 overwrites it
  }

  // ---- epilogue: masked exp2, col-reduce, combine B1+B2 sums, store partial ----
  const bool isN2O = (sel == 0);
  int tc[8];
#pragma unroll
  for (int fc = 0; fc < 8; ++fc) tc[fc] = tgt[jb + fc * 16 + lrow];
  float* rsum = (float*)lA;  // 2*256 floats, reuse staging LDS (all reads done)
#pragma unroll
  for (int fr = 0; fr < 4; ++fr) {
#pragma unroll
    for (int reg = 0; reg < 4; ++reg) {
      const int gr = row0 + wr * 64 + fr * 16 + lkg * 4 + reg;
      const int trv = tgt[gr];
      float s = 0.0f;
#pragma unroll
      for (int fc = 0; fc < 8; ++fc) {
        const int gc = jb + fc * 16 + lrow;
        const float p = __builtin_amdgcn_exp2f(fmaf(acc[fr][fc][reg], CEXP, EOFF));
        // n2o: keep diagonal (stands in for the explicit pos column), drop same-label
        // n2n: drop all same-label (diagonal auto-dropped, labels equal)
        const bool keep = (trv != tc[fc]) || (isN2O && gr == gc);
        s += keep ? p : 0.0f;
      }
      s += __shfl_xor(s, 1);
      s += __shfl_xor(s, 2);
      s += __shfl_xor(s, 4);
      s += __shfl_xor(s, 8);
      if (lrow == 0) rsum[sel * 256 + wr * 64 + fr * 16 + lkg * 4 + reg] = s;
    }
  }
  barrier_raw();
  if (tid < 256) {
    const float v = rsum[tid] + rsum[256 + tid];
    partial[(size_t)(row0 + tid) * 32 + nt] = v;
  }
}

// ---------------- kernel 3: per-row finalize (32 blocks) ----------------
__global__ __launch_bounds__(256) void k_final(const float* __restrict__ partial,
                                               const float* __restrict__ pos,
                                               float* __restrict__ bsum) {
  const int t = threadIdx.x;
  const int r = blockIdx.x * 128 + (t >> 1);
  const int half = t & 1;
  const float4* p = (const float4*)(partial + (size_t)r * 32 + half * 16);
  float v = 0.0f;
#pragma unroll
  for (int q = 0; q < 4; ++q) {
    const float4 a = p[q];
    v += (a.x + a.y) + (a.z + a.w);
  }
  v += __shfl_xor(v, 1);  // combine the two halves of the row
  float contrib = (half == 0)
                      ? (LSE_BASE + __builtin_amdgcn_logf(v) * LN2 - 100.0f * pos[r])
                      : 0.0f;
  contrib = wave_sum(contrib);
  __shared__ float red[4];
  if ((t & 63) == 0) red[t >> 6] = contrib;
  __syncthreads();
  if (t == 0) bsum[blockIdx.x] = (red[0] + red[1]) + (red[2] + red[3]);
}

// ---------------- kernel 4: mean of 32 block sums ----------------
__global__ __launch_bounds__(64) void k_mean(const float* __restrict__ bsum,
                                             float* __restrict__ out) {
  float s = (threadIdx.x < 32) ? bsum[threadIdx.x] : 0.0f;
  s = wave_sum(s);
  if (threadIdx.x == 0) out[0] = s * (1.0f / (float)BB);
}

extern "C" void kernel_launch(void* const* d_in, const int* in_sizes, int n_in,
                              void* d_out, int out_size, void* d_ws, size_t ws_size,
                              hipStream_t stream) {
  const float* feat = (const float*)d_in[0];
  const float* feat_old = (const float*)d_in[1];
  const int* targets = (const int*)d_in[2];
  float* out = (float*)d_out;
  char* ws = (char*)d_ws;

  u16* fnb = (u16*)ws;                                           // 4 MB
  u16* fob = (u16*)(ws + 4u * 1024 * 1024);                      // 4 MB
  float* pos = (float*)(ws + 8u * 1024 * 1024);                  // 16 KB
  float* partial = (float*)(ws + 8u * 1024 * 1024 + 16 * 1024);  // 512 KB
  float* bsum = (float*)(ws + 8u * 1024 * 1024 + 544 * 1024);    // 128 B

  k_norm<<<BB / 4, 256, 0, stream>>>(feat, feat_old, fnb, fob, pos);
  k_fused<<<512, 512, 0, stream>>>(fnb, fob, targets, partial);
  k_final<<<32, 256, 0, stream>>>(partial, pos, bsum);
  k_mean<<<1, 64, 0, stream>>>(bsum, out);
}